// Round 5
// baseline (64.765 us; speedup 1.0000x reference)
//
#include <hip/hip_runtime.h>
#include <hip/hip_bf16.h>

#define B_ 16
#define C_ 64
#define HW_ 4096              // H*W
#define K_ 1024
#define N_ 65536              // B*H*W pixels
#define NELEM 4194304         // B*C*H*W
#define NBLK 1024             // N_/64 : 64 pixels per block

typedef __attribute__((ext_vector_type(8))) short bf16x8;
typedef __attribute__((ext_vector_type(4))) float f32x4;

static __device__ __forceinline__ short f2bf(float f) {
    __hip_bfloat16 h = __float2bfloat16(f);           // RNE, native cvt
    return (short)__builtin_bit_cast(unsigned short, h);
}

// ---- kernel 1: emb -> bf16(-2*emb) copy + e2' = 1 + |e|^2 ----------------
__global__ __launch_bounds__(256) void vq_prep(const float* __restrict__ emb,
                                               float* __restrict__ e2,
                                               short* __restrict__ emb_bf) {
    const int id = blockIdx.x * 256 + threadIdx.x;
    {   // -2x scale is exact in bf16 (sign + exponent shift)
        const float4* src = (const float4*)(emb + (size_t)id * 8);
        float4 a = src[0], b = src[1];
        bf16x8 v;
        v[0]=f2bf(-2.f*a.x); v[1]=f2bf(-2.f*a.y); v[2]=f2bf(-2.f*a.z); v[3]=f2bf(-2.f*a.w);
        v[4]=f2bf(-2.f*b.x); v[5]=f2bf(-2.f*b.y); v[6]=f2bf(-2.f*b.z); v[7]=f2bf(-2.f*b.w);
        *(bf16x8*)(emb_bf + (size_t)id * 8) = v;
    }
    if (id < K_) {
        const float4* row = (const float4*)(emb + (size_t)id * C_);
        float s0 = 0.f, s1 = 0.f, s2 = 0.f, s3 = 0.f;
        #pragma unroll
        for (int i = 0; i < C_ / 4; ++i) {
            float4 v = row[i];
            s0 = fmaf(v.x, v.x, s0);
            s1 = fmaf(v.y, v.y, s1);
            s2 = fmaf(v.z, v.z, s2);
            s3 = fmaf(v.w, v.w, s3);
        }
        e2[id] = 1.0f + ((s0 + s1) + (s2 + s3));   // keeps dist' > 0
    }
}

// ---- kernel 2: fused MFMA argmin + gather + q_st + loss ------------------
// Block = 512 thr = 8 waves, owns 64 consecutive pixels (same b).
// z is staged ONCE into XOR-swizzled LDS bf16 [pixel][channel].
// Wave w scans K-octant [w*128, w*128+128):
//   A = 16-code tile of (-2*emb) bf16 (register double-buffered)
//   B = 16-pixel z tile from LDS; C-init = e2' = 1+|e|^2
//   => D[row=code][col=pixel] = 1 + |e|^2 - 2 z.e  (strictly positive)
// Select: sortable int = (bits(dist) & ~1023) | k ; argmin = v_min_i32.
__global__ __launch_bounds__(512, 6) void vq_main(const float* __restrict__ z,
                                                  const float* __restrict__ emb,
                                                  const short* __restrict__ emb_bf,
                                                  const float* __restrict__ e2,
                                                  float* __restrict__ out,
                                                  float* __restrict__ psum) {
    __shared__ short zlds[64 * 64];    // 8 KB, [px][ch], byte ^= (px&7)<<4
    __shared__ int   smin[8][64];
    __shared__ int   cidx[64];
    __shared__ float red[8];

    const int tid  = threadIdx.x;
    const int lane = tid & 63;
    const int wave = __builtin_amdgcn_readfirstlane(tid >> 6);  // 0..7
    const int prow = lane & 15;        // code-in-tile row
    const int kgrp = lane >> 4;        // k-group 0..3

    const int blk = blockIdx.x;        // 0..1023
    const int b   = blk >> 6;          // 64 blocks per image
    const int hw0 = (blk & 63) * 64;
    const float* zp = z + (size_t)b * C_ * HW_ + hw0;   // + c*HW_ + p

    // ---- stage z -> LDS bf16 (each thread: 8 channels of one pixel) ----
    {
        const int p  = tid & 63;
        const int c0 = tid >> 6;                // 0..7
        const float* zsrc = zp + (size_t)(c0 * 8) * HW_ + p;
        bf16x8 pack;
        #pragma unroll
        for (int i = 0; i < 8; ++i) pack[i] = f2bf(zsrc[(size_t)i * HW_]);
        const int wb = (p * 128 + ((c0 * 16) ^ ((p & 7) << 4))) >> 1;
        *(bf16x8*)(zlds + wb) = pack;
    }
    __syncthreads();

    // ---- z fragments (B operand): 4 pixel-tiles x 2 K-halves ----
    bf16x8 zf[4][2];
    #pragma unroll
    for (int pt = 0; pt < 4; ++pt) {
        const int pp = pt * 16 + prow;
        #pragma unroll
        for (int ks = 0; ks < 2; ++ks) {
            const int rb = (pp * 128 + ((ks * 64 + kgrp * 16) ^ ((pp & 7) << 4))) >> 1;
            zf[pt][ks] = *(const bf16x8*)(zlds + rb);
        }
    }

    // ---- per-wave argmin over its 128-code octant ----
    const int kq = wave * 128;
    const short* ebase = emb_bf + (size_t)(kq + prow) * C_ + kgrp * 8;
    const float* e2p   = e2 + kq + kgrp * 4;
    int best[4] = {0x7FFFFFFF, 0x7FFFFFFF, 0x7FFFFFFF, 0x7FFFFFFF};

    bf16x8 a0 = *(const bf16x8*)(ebase);
    bf16x8 a1 = *(const bf16x8*)(ebase + 32);
    f32x4  ev = *(const f32x4*)(e2p);

    #pragma unroll
    for (int ct = 0; ct < 8; ++ct) {
        const int ctn = (ct + 1) & 7;          // wrap on last iter (harmless)
        const bf16x8 a0n = *(const bf16x8*)(ebase + ctn * 1024);
        const bf16x8 a1n = *(const bf16x8*)(ebase + ctn * 1024 + 32);
        const f32x4  evn = *(const f32x4*)(e2p + ctn * 16);

        const int kcode = kq + ct * 16 + kgrp * 4;
        #pragma unroll
        for (int pt = 0; pt < 4; ++pt) {
            f32x4 acc = ev;
            acc = __builtin_amdgcn_mfma_f32_16x16x32_bf16(a0, zf[pt][0], acc, 0, 0, 0);
            acc = __builtin_amdgcn_mfma_f32_16x16x32_bf16(a1, zf[pt][1], acc, 0, 0, 0);
            #pragma unroll
            for (int r = 0; r < 4; ++r) {
                const int s = (__builtin_bit_cast(int, acc[r]) & ~1023) | (kcode + r);
                best[pt] = min(best[pt], s);
            }
        }
        a0 = a0n; a1 = a1n; ev = evn;
    }

    // cross-lane combine over k-groups (bits 4,5 of lane)
    #pragma unroll
    for (int pt = 0; pt < 4; ++pt) {
        #pragma unroll
        for (int m = 16; m <= 32; m <<= 1)
            best[pt] = min(best[pt], __shfl_xor(best[pt], m));
        if (kgrp == 0) smin[wave][pt * 16 + prow] = best[pt];
    }
    __syncthreads();

    // cross-wave combine (8 octants)
    if (tid < 64) {
        int bb = min(min(min(smin[0][tid], smin[1][tid]),
                         min(smin[2][tid], smin[3][tid])),
                     min(min(smin[4][tid], smin[5][tid]),
                         min(smin[6][tid], smin[7][tid])));
        cidx[tid] = bb & 1023;
    }
    __syncthreads();

    // ---- output phase: q_st = z + (q - z), partial loss ----
    float* op = out + (size_t)b * C_ * HW_ + hw0;
    const int p  = tid & 63;
    const int c0 = tid >> 6;                  // 0..7
    const float* qrow = emb + (size_t)cidx[p] * C_;
    float sq = 0.f;
    #pragma unroll
    for (int i = 0; i < 8; ++i) {
        const int c = c0 * 8 + i;
        const float zv   = zp[(size_t)c * HW_ + p];
        const float q    = qrow[c];
        const float diff = q - zv;            // matches reference op order
        op[(size_t)c * HW_ + p] = zv + diff;  // q_st = z + (q - z)
        sq = fmaf(diff, diff, sq);
    }
    #pragma unroll
    for (int off = 32; off; off >>= 1) sq += __shfl_xor(sq, off);
    if (lane == 0) red[wave] = sq;
    __syncthreads();
    if (tid == 0) {
        float s = 0.f;
        #pragma unroll
        for (int w2 = 0; w2 < 8; ++w2) s += red[w2];
        psum[blk] = s;
    }
}

// ---- kernel 3: reduce partials -> loss -----------------------------------
__global__ __launch_bounds__(256) void vq_finalize(const float* __restrict__ psum,
                                                   float* __restrict__ out) {
    const int tid = threadIdx.x;
    float s = 0.f;
    #pragma unroll
    for (int i = 0; i < 4; ++i) s += psum[i * 256 + tid];
    #pragma unroll
    for (int off = 32; off; off >>= 1) s += __shfl_xor(s, off);
    __shared__ float red[4];
    if ((tid & 63) == 0) red[tid >> 6] = s;
    __syncthreads();
    if (tid == 0)
        out[NELEM] = 1.25f * ((red[0] + red[1]) + (red[2] + red[3])) / (float)NELEM;
}

extern "C" void kernel_launch(void* const* d_in, const int* in_sizes, int n_in,
                              void* d_out, int out_size, void* d_ws, size_t ws_size,
                              hipStream_t stream) {
    const float* z   = (const float*)d_in[0];   // [16,64,64,64]
    const float* emb = (const float*)d_in[1];   // [1024,64]
    float* out = (float*)d_out;                 // [4194304 q_st] ++ [1 loss]

    float* psum   = (float*)d_ws;               // 1024 floats
    float* e2     = psum + K_;                  // 1024 floats (e2' = 1+|e|^2)
    short* emb_bf = (short*)(e2 + K_);          // 65536 bf16 of -2*emb

    vq_prep    <<<(K_ * C_) / (256 * 8), 256, 0, stream>>>(emb, e2, emb_bf);
    vq_main    <<<NBLK, 512, 0, stream>>>(z, emb, emb_bf, e2, out, psum);
    vq_finalize<<<1,    256, 0, stream>>>(psum, out);
}

// Round 6
// 37.884 us; speedup vs baseline: 1.7096x; 1.7096x over previous
//
#include <hip/hip_runtime.h>
#include <hip/hip_bf16.h>

#define B_ 16
#define C_ 64
#define HW_ 4096              // H*W
#define K_ 1024
#define N_ 65536              // B*H*W pixels
#define NELEM 4194304         // B*C*H*W
#define NBLK 1024             // N_/64 : 64 pixels per block

typedef __attribute__((ext_vector_type(8))) short bf16x8;
typedef __attribute__((ext_vector_type(4))) float f32x4;

static __device__ __forceinline__ short f2bf(float f) {
    __hip_bfloat16 h = __float2bfloat16(f);           // RNE, native cvt
    return (short)__builtin_bit_cast(unsigned short, h);
}

// ---- kernel 1: emb -> bf16(-2*emb) copy + e2' = 1 + |e|^2 ----------------
__global__ __launch_bounds__(256) void vq_prep(const float* __restrict__ emb,
                                               float* __restrict__ e2,
                                               short* __restrict__ emb_bf) {
    const int id = blockIdx.x * 256 + threadIdx.x;
    {   // -2x scale is exact in bf16 (sign + exponent shift)
        const float4* src = (const float4*)(emb + (size_t)id * 8);
        float4 a = src[0], b = src[1];
        bf16x8 v;
        v[0]=f2bf(-2.f*a.x); v[1]=f2bf(-2.f*a.y); v[2]=f2bf(-2.f*a.z); v[3]=f2bf(-2.f*a.w);
        v[4]=f2bf(-2.f*b.x); v[5]=f2bf(-2.f*b.y); v[6]=f2bf(-2.f*b.z); v[7]=f2bf(-2.f*b.w);
        *(bf16x8*)(emb_bf + (size_t)id * 8) = v;
    }
    if (id < K_) {
        const float4* row = (const float4*)(emb + (size_t)id * C_);
        float s0 = 0.f, s1 = 0.f, s2 = 0.f, s3 = 0.f;
        #pragma unroll
        for (int i = 0; i < C_ / 4; ++i) {
            float4 v = row[i];
            s0 = fmaf(v.x, v.x, s0);
            s1 = fmaf(v.y, v.y, s1);
            s2 = fmaf(v.z, v.z, s2);
            s3 = fmaf(v.w, v.w, s3);
        }
        e2[id] = 1.0f + ((s0 + s1) + (s2 + s3));   // keeps dist' > 0
    }
}

// ---- kernel 2: fused MFMA argmin + gather + q_st + loss ------------------
// Block = 512 thr = 8 waves, owns 64 consecutive pixels (same b).
// z is staged ONCE into XOR-swizzled LDS bf16 [pixel][channel].
// Wave w scans K-octant [w*128, w*128+128):
//   A = 16-code tile of (-2*emb) bf16 (register double-buffered)
//   B = 16-pixel z tile from LDS; C-init = e2' = 1+|e|^2
//   => D[row=code][col=pixel] = 1 + |e|^2 - 2 z.e  (strictly positive)
// Select: sortable int = (bits(dist) & ~1023) | k ; argmin = v_min_i32.
// launch_bounds (512,4): VGPR cap 128 — natural use ~90, NO scratch spill
// (the R5 regression was (512,6) -> 85-reg cap -> 230 MB scratch traffic).
__global__ __launch_bounds__(512, 4) void vq_main(const float* __restrict__ z,
                                                  const float* __restrict__ emb,
                                                  const short* __restrict__ emb_bf,
                                                  const float* __restrict__ e2,
                                                  float* __restrict__ out,
                                                  float* __restrict__ psum) {
    __shared__ short zlds[64 * 64];    // 8 KB, [px][ch], byte ^= (px&7)<<4
    __shared__ int   smin[8][64];
    __shared__ int   cidx[64];
    __shared__ float red[8];

    const int tid  = threadIdx.x;
    const int lane = tid & 63;
    const int wave = __builtin_amdgcn_readfirstlane(tid >> 6);  // 0..7
    const int prow = lane & 15;        // code-in-tile row
    const int kgrp = lane >> 4;        // k-group 0..3

    const int blk = blockIdx.x;        // 0..1023
    const int b   = blk >> 6;          // 64 blocks per image
    const int hw0 = (blk & 63) * 64;
    const float* zp = z + (size_t)b * C_ * HW_ + hw0;   // + c*HW_ + p

    // ---- stage z -> LDS bf16 (each thread: 8 channels of one pixel) ----
    {
        const int p  = tid & 63;
        const int c0 = tid >> 6;                // 0..7
        const float* zsrc = zp + (size_t)(c0 * 8) * HW_ + p;
        bf16x8 pack;
        #pragma unroll
        for (int i = 0; i < 8; ++i) pack[i] = f2bf(zsrc[(size_t)i * HW_]);
        const int wb = (p * 128 + ((c0 * 16) ^ ((p & 7) << 4))) >> 1;
        *(bf16x8*)(zlds + wb) = pack;
    }
    __syncthreads();

    // ---- z fragments (B operand): 4 pixel-tiles x 2 K-halves ----
    bf16x8 zf[4][2];
    #pragma unroll
    for (int pt = 0; pt < 4; ++pt) {
        const int pp = pt * 16 + prow;
        #pragma unroll
        for (int ks = 0; ks < 2; ++ks) {
            const int rb = (pp * 128 + ((ks * 64 + kgrp * 16) ^ ((pp & 7) << 4))) >> 1;
            zf[pt][ks] = *(const bf16x8*)(zlds + rb);
        }
    }

    // ---- per-wave argmin over its 128-code octant ----
    const int kq = wave * 128;
    const short* ebase = emb_bf + (size_t)(kq + prow) * C_ + kgrp * 8;
    const float* e2p   = e2 + kq + kgrp * 4;
    int best[4] = {0x7FFFFFFF, 0x7FFFFFFF, 0x7FFFFFFF, 0x7FFFFFFF};

    bf16x8 a0 = *(const bf16x8*)(ebase);
    bf16x8 a1 = *(const bf16x8*)(ebase + 32);
    f32x4  ev = *(const f32x4*)(e2p);

    #pragma unroll
    for (int ct = 0; ct < 8; ++ct) {
        const int ctn = (ct + 1) & 7;          // wrap on last iter (harmless)
        const bf16x8 a0n = *(const bf16x8*)(ebase + ctn * 1024);
        const bf16x8 a1n = *(const bf16x8*)(ebase + ctn * 1024 + 32);
        const f32x4  evn = *(const f32x4*)(e2p + ctn * 16);

        const int kcode = kq + ct * 16 + kgrp * 4;
        #pragma unroll
        for (int pt = 0; pt < 4; ++pt) {
            f32x4 acc = ev;
            acc = __builtin_amdgcn_mfma_f32_16x16x32_bf16(a0, zf[pt][0], acc, 0, 0, 0);
            acc = __builtin_amdgcn_mfma_f32_16x16x32_bf16(a1, zf[pt][1], acc, 0, 0, 0);
            #pragma unroll
            for (int r = 0; r < 4; ++r) {
                const int s = (__builtin_bit_cast(int, acc[r]) & ~1023) | (kcode + r);
                best[pt] = min(best[pt], s);
            }
        }
        a0 = a0n; a1 = a1n; ev = evn;
    }

    // cross-lane combine over k-groups (bits 4,5 of lane)
    #pragma unroll
    for (int pt = 0; pt < 4; ++pt) {
        #pragma unroll
        for (int m = 16; m <= 32; m <<= 1)
            best[pt] = min(best[pt], __shfl_xor(best[pt], m));
        if (kgrp == 0) smin[wave][pt * 16 + prow] = best[pt];
    }
    __syncthreads();

    // cross-wave combine (8 octants)
    if (tid < 64) {
        int bb = min(min(min(smin[0][tid], smin[1][tid]),
                         min(smin[2][tid], smin[3][tid])),
                     min(min(smin[4][tid], smin[5][tid]),
                         min(smin[6][tid], smin[7][tid])));
        cidx[tid] = bb & 1023;
    }
    __syncthreads();

    // ---- output phase: q_st = z + (q - z), partial loss ----
    float* op = out + (size_t)b * C_ * HW_ + hw0;
    const int p  = tid & 63;
    const int c0 = tid >> 6;                  // 0..7
    const float* qrow = emb + (size_t)cidx[p] * C_;
    float sq = 0.f;
    #pragma unroll
    for (int i = 0; i < 8; ++i) {
        const int c = c0 * 8 + i;
        const float zv   = zp[(size_t)c * HW_ + p];
        const float q    = qrow[c];
        const float diff = q - zv;            // matches reference op order
        op[(size_t)c * HW_ + p] = zv + diff;  // q_st = z + (q - z)
        sq = fmaf(diff, diff, sq);
    }
    #pragma unroll
    for (int off = 32; off; off >>= 1) sq += __shfl_xor(sq, off);
    if (lane == 0) red[wave] = sq;
    __syncthreads();
    if (tid == 0) {
        float s = 0.f;
        #pragma unroll
        for (int w2 = 0; w2 < 8; ++w2) s += red[w2];
        psum[blk] = s;
    }
}

// ---- kernel 3: reduce partials -> loss -----------------------------------
__global__ __launch_bounds__(256) void vq_finalize(const float* __restrict__ psum,
                                                   float* __restrict__ out) {
    const int tid = threadIdx.x;
    float s = 0.f;
    #pragma unroll
    for (int i = 0; i < 4; ++i) s += psum[i * 256 + tid];
    #pragma unroll
    for (int off = 32; off; off >>= 1) s += __shfl_xor(s, off);
    __shared__ float red[4];
    if ((tid & 63) == 0) red[tid >> 6] = s;
    __syncthreads();
    if (tid == 0)
        out[NELEM] = 1.25f * ((red[0] + red[1]) + (red[2] + red[3])) / (float)NELEM;
}

extern "C" void kernel_launch(void* const* d_in, const int* in_sizes, int n_in,
                              void* d_out, int out_size, void* d_ws, size_t ws_size,
                              hipStream_t stream) {
    const float* z   = (const float*)d_in[0];   // [16,64,64,64]
    const float* emb = (const float*)d_in[1];   // [1024,64]
    float* out = (float*)d_out;                 // [4194304 q_st] ++ [1 loss]

    float* psum   = (float*)d_ws;               // 1024 floats
    float* e2     = psum + K_;                  // 1024 floats (e2' = 1+|e|^2)
    short* emb_bf = (short*)(e2 + K_);          // 65536 bf16 of -2*emb

    vq_prep    <<<(K_ * C_) / (256 * 8), 256, 0, stream>>>(emb, e2, emb_bf);
    vq_main    <<<NBLK, 512, 0, stream>>>(z, emb, emb_bf, e2, out, psum);
    vq_finalize<<<1,    256, 0, stream>>>(psum, out);
}

// Round 7
// 27.409 us; speedup vs baseline: 2.3629x; 1.3822x over previous
//
#include <hip/hip_runtime.h>
#include <hip/hip_bf16.h>

#define B_ 16
#define C_ 64
#define HW_ 4096              // H*W
#define K_ 1024
#define NELEM 4194304         // B*C*H*W
#define NBLK 512              // 128 pixels per block
#define PXB 128

typedef __attribute__((ext_vector_type(8))) short bf16x8;
typedef __attribute__((ext_vector_type(4))) float f32x4;
typedef unsigned int u32;

static __device__ __forceinline__ short f2bf(float f) {
    __hip_bfloat16 h = __float2bfloat16(f);           // RNE, native cvt
    return (short)__builtin_bit_cast(unsigned short, h);
}

// global -> LDS async copy, 16B per lane. Dest is WAVE-UNIFORM base (HW adds
// lane*16); src is per-lane.
static __device__ __forceinline__ void gl_lds16(const short* g, short* l) {
    __builtin_amdgcn_global_load_lds(
        (const __attribute__((address_space(1))) u32*)g,
        (__attribute__((address_space(3))) u32*)l, 16, 0, 0);
}

// ---- kernel 1: emb -> PRE-SWIZZLED bf16(-2*emb) + e2' = 1 + |e|^2 --------
// Swizzle: byte col within the 128B row XORed with (code&7)<<4, so that a
// LINEAR global_load_lds copy lands bank-balanced for the MFMA ds_reads.
__global__ __launch_bounds__(256) void vq_prep(const float* __restrict__ emb,
                                               float* __restrict__ e2,
                                               short* __restrict__ emb_swz) {
    const int id = blockIdx.x * 256 + threadIdx.x;    // 0..8191
    {   // -2x scale is exact in bf16 (sign + exponent shift)
        const int code = id >> 3;
        const int c16  = id & 7;                      // 16B group in row
        const float4* src = (const float4*)(emb + (size_t)id * 8);
        float4 a = src[0], b = src[1];
        bf16x8 v;
        v[0]=f2bf(-2.f*a.x); v[1]=f2bf(-2.f*a.y); v[2]=f2bf(-2.f*a.z); v[3]=f2bf(-2.f*a.w);
        v[4]=f2bf(-2.f*b.x); v[5]=f2bf(-2.f*b.y); v[6]=f2bf(-2.f*b.z); v[7]=f2bf(-2.f*b.w);
        const int off = code * 64 + ((((c16 * 16) ^ ((code & 7) << 4))) >> 1);
        *(bf16x8*)(emb_swz + off) = v;
    }
    if (id < K_) {
        const float4* row = (const float4*)(emb + (size_t)id * C_);
        float s0 = 0.f, s1 = 0.f, s2 = 0.f, s3 = 0.f;
        #pragma unroll
        for (int i = 0; i < C_ / 4; ++i) {
            float4 v = row[i];
            s0 = fmaf(v.x, v.x, s0);
            s1 = fmaf(v.y, v.y, s1);
            s2 = fmaf(v.z, v.z, s2);
            s3 = fmaf(v.w, v.w, s3);
        }
        e2[id] = 1.0f + ((s0 + s1) + (s2 + s3));   // keeps dist' > 0
    }
}

// ---- kernel 2: fused MFMA argmin + gather + q_st + loss ------------------
// Block = 512 thr = 8 waves, owns 128 consecutive pixels (same b).
// Wave w owns pixel-tile w (16 px) and scans ALL 1024 codes.
// emb chunks (128 codes, 16 KB) double-buffered in LDS via global_load_lds
// (2-phase pipeline: stage t+1, compute t, one barrier per chunk).
//   A = 16-code tile of (-2*emb); B = 16-pixel z tile; C-init = e2'
//   => D[row=code][col=pixel] = 1 + |e|^2 - 2 z.e  (positive)
// Select: sortable int = (bits(dist) & ~1023) | k ; argmin = v_min_i32.
__global__ __launch_bounds__(512, 4) void vq_main(const float* __restrict__ z,
                                                  const float* __restrict__ emb,
                                                  const short* __restrict__ emb_swz,
                                                  const float* __restrict__ e2,
                                                  float* __restrict__ out,
                                                  float* __restrict__ psum) {
    __shared__ short zlds[PXB * 64];      // 16 KB, [px][ch], col ^= (px&7)<<4
    __shared__ short embuf[2][8192];      // 2 x 16 KB chunk double-buffer
    __shared__ float e2lds[K_];           // 4 KB
    __shared__ int   cidx[PXB];
    __shared__ float red[8];

    const int tid  = threadIdx.x;
    const int lane = tid & 63;
    const int wave = __builtin_amdgcn_readfirstlane(tid >> 6);  // 0..7
    const int prow = lane & 15;        // code-in-tile row
    const int kgrp = lane >> 4;        // k-group 0..3

    const int blk = blockIdx.x;        // 0..511
    const int b   = blk >> 5;          // 32 blocks per image
    const int hw0 = (blk & 31) * PXB;
    const float* zp = z + (size_t)b * C_ * HW_ + hw0;   // + c*HW_ + p

    // ---- stage z -> swizzled LDS bf16 (each thread: 16 ch of one pixel) --
    {
        const int p  = tid & 127;
        const int c0 = tid >> 7;               // 0..3
        #pragma unroll
        for (int h = 0; h < 2; ++h) {
            const int cb = c0 * 16 + h * 8;    // channel base
            bf16x8 pack;
            #pragma unroll
            for (int i = 0; i < 8; ++i) pack[i] = f2bf(zp[(size_t)(cb + i) * HW_ + p]);
            const int wb = (p * 128 + ((cb * 2) ^ ((p & 7) << 4))) >> 1;
            *(bf16x8*)(zlds + wb) = pack;
        }
    }
    // ---- stage e2' (1024 floats) ----
    e2lds[tid]       = e2[tid];
    e2lds[tid + 512] = e2[tid + 512];
    // ---- stage emb chunk 0 (16 KB: 8 waves x 2 x 1KB) ----
    {
        short* dst = embuf[0] + wave * 512;             // shorts: 1KB/wave
        const short* s0 = emb_swz + wave * 512 + lane * 8;
        gl_lds16(s0, dst);
        gl_lds16(s0 + 4096, dst + 4096);                // +8KB
    }
    __syncthreads();

    // ---- z fragments (B operand) for this wave's 16-pixel tile ----
    const int pp = wave * 16 + prow;
    const int r0 = (pp * 128 + ((kgrp * 16) ^ ((pp & 7) << 4))) >> 1;
    const int r1 = (pp * 128 + ((64 + kgrp * 16) ^ ((pp & 7) << 4))) >> 1;
    const bf16x8 zf0 = *(const bf16x8*)(zlds + r0);
    const bf16x8 zf1 = *(const bf16x8*)(zlds + r1);

    // lane-constant swizzle (ct*16 = 0 mod 8 -> code&7 == prow&7)
    const int sa = ((kgrp * 16) ^ ((prow & 7) << 4));
    const int sb = ((64 + kgrp * 16) ^ ((prow & 7) << 4));
    const int ra0 = (prow * 128 + sa) >> 1;    // + ct*1024 shorts per tile
    const int rb0 = (prow * 128 + sb) >> 1;

    int best = 0x7FFFFFFF;
    int buf = 0;
    for (int chunk = 0; chunk < 8; ++chunk) {
        if (chunk < 7) {   // issue next-chunk stage BEFORE compute (T3)
            short* dst = embuf[buf ^ 1] + wave * 512;
            const short* s0 = emb_swz + (chunk + 1) * 8192 + wave * 512 + lane * 8;
            gl_lds16(s0, dst);
            gl_lds16(s0 + 4096, dst + 4096);
        }
        const short* eb = embuf[buf];
        const int keb = chunk * 128 + kgrp * 4;
        #pragma unroll
        for (int ct = 0; ct < 8; ++ct) {
            const bf16x8 a0 = *(const bf16x8*)(eb + ra0 + ct * 1024);
            const bf16x8 a1 = *(const bf16x8*)(eb + rb0 + ct * 1024);
            const int ke = keb + ct * 16;
            f32x4 acc = *(const f32x4*)(e2lds + ke);
            acc = __builtin_amdgcn_mfma_f32_16x16x32_bf16(a0, zf0, acc, 0, 0, 0);
            acc = __builtin_amdgcn_mfma_f32_16x16x32_bf16(a1, zf1, acc, 0, 0, 0);
            #pragma unroll
            for (int r = 0; r < 4; ++r) {
                const int s = (__builtin_bit_cast(int, acc[r]) & ~1023) | (ke + r);
                best = min(best, s);
            }
        }
        __syncthreads();   // stage landed (vmcnt0) + compute done -> swap
        buf ^= 1;
    }

    // cross-lane combine over k-groups (bits 4,5 of lane)
    #pragma unroll
    for (int m = 16; m <= 32; m <<= 1)
        best = min(best, __shfl_xor(best, m));
    if (kgrp == 0) cidx[pp] = best & 1023;
    __syncthreads();

    // ---- output phase: q_st = z + (q - z), partial loss ----
    float* op = out + (size_t)b * C_ * HW_ + hw0;
    const int p  = tid & 127;
    const int c0 = tid >> 7;                  // 0..3
    const float* qrow = emb + (size_t)cidx[p] * C_;
    float sq = 0.f;
    #pragma unroll
    for (int i = 0; i < 16; ++i) {
        const int c = c0 * 16 + i;
        const float zv   = zp[(size_t)c * HW_ + p];
        const float q    = qrow[c];
        const float diff = q - zv;            // matches reference op order
        op[(size_t)c * HW_ + p] = zv + diff;  // q_st = z + (q - z)
        sq = fmaf(diff, diff, sq);
    }
    #pragma unroll
    for (int off = 32; off; off >>= 1) sq += __shfl_xor(sq, off);
    if (lane == 0) red[wave] = sq;
    __syncthreads();
    if (tid == 0) {
        float s = 0.f;
        #pragma unroll
        for (int w2 = 0; w2 < 8; ++w2) s += red[w2];
        psum[blk] = s;
    }
}

// ---- kernel 3: reduce partials -> loss -----------------------------------
__global__ __launch_bounds__(256) void vq_finalize(const float* __restrict__ psum,
                                                   float* __restrict__ out) {
    const int tid = threadIdx.x;
    float s = psum[tid] + psum[tid + 256];
    #pragma unroll
    for (int off = 32; off; off >>= 1) s += __shfl_xor(s, off);
    __shared__ float red[4];
    if ((tid & 63) == 0) red[tid >> 6] = s;
    __syncthreads();
    if (tid == 0)
        out[NELEM] = 1.25f * ((red[0] + red[1]) + (red[2] + red[3])) / (float)NELEM;
}

extern "C" void kernel_launch(void* const* d_in, const int* in_sizes, int n_in,
                              void* d_out, int out_size, void* d_ws, size_t ws_size,
                              hipStream_t stream) {
    const float* z   = (const float*)d_in[0];   // [16,64,64,64]
    const float* emb = (const float*)d_in[1];   // [1024,64]
    float* out = (float*)d_out;                 // [4194304 q_st] ++ [1 loss]

    float* psum    = (float*)d_ws;              // 512 floats
    float* e2      = psum + NBLK;               // 1024 floats (e2' = 1+|e|^2)
    short* emb_swz = (short*)(e2 + K_);         // 65536 bf16, pre-swizzled -2*emb

    vq_prep    <<<(K_ * C_) / (256 * 8), 256, 0, stream>>>(emb, e2, emb_swz);
    vq_main    <<<NBLK, 512, 0, stream>>>(z, emb, emb_swz, e2, out, psum);
    vq_finalize<<<1,    256, 0, stream>>>(psum, out);
}

// Round 8
// 25.550 us; speedup vs baseline: 2.5348x; 1.0728x over previous
//
#include <hip/hip_runtime.h>
#include <hip/hip_bf16.h>

#define B_ 16
#define C_ 64
#define HW_ 4096              // H*W
#define K_ 1024
#define NELEM 4194304         // B*C*H*W
#define NBLK 512              // 128 pixels per block
#define PXB 128

typedef __attribute__((ext_vector_type(8))) short bf16x8;
typedef __attribute__((ext_vector_type(4))) float f32x4;
typedef unsigned int u32;

static __device__ __forceinline__ short f2bf(float f) {
    __hip_bfloat16 h = __float2bfloat16(f);           // RNE, native cvt
    return (short)__builtin_bit_cast(unsigned short, h);
}

// global -> LDS async copy, 16B per lane; dest is wave-uniform base.
static __device__ __forceinline__ void gl_lds16(const short* g, short* l) {
    __builtin_amdgcn_global_load_lds(
        (const __attribute__((address_space(1))) u32*)g,
        (__attribute__((address_space(3))) u32*)l, 16, 0, 0);
}

// Code permutation: orig k = q*256 + ch*32 + t  ->  pos n = ch*128 + q*32 + t.
// Chunk ch (128 codes) then contains 32 codes of EVERY quadrant, so all 4
// quadrant-waves work on every streamed chunk. n&7 == t&7 == k&7.
static __device__ __forceinline__ int kperm(int k) {
    const int q = k >> 8, ch = (k >> 5) & 7, t = k & 31;
    return ch * 128 + q * 32 + t;
}

// ---- kernel 1: emb -> permuted+swizzled bf16(-2*emb) + permuted e2' ------
__global__ __launch_bounds__(256) void vq_prep(const float* __restrict__ emb,
                                               float* __restrict__ e2,
                                               short* __restrict__ emb_swz) {
    const int id = blockIdx.x * 256 + threadIdx.x;    // 0..8191
    {   // -2x scale is exact in bf16 (sign + exponent shift)
        const int code = id >> 3;
        const int c16  = id & 7;                      // 16B group in row
        const float4* src = (const float4*)(emb + (size_t)id * 8);
        float4 a = src[0], b = src[1];
        bf16x8 v;
        v[0]=f2bf(-2.f*a.x); v[1]=f2bf(-2.f*a.y); v[2]=f2bf(-2.f*a.z); v[3]=f2bf(-2.f*a.w);
        v[4]=f2bf(-2.f*b.x); v[5]=f2bf(-2.f*b.y); v[6]=f2bf(-2.f*b.z); v[7]=f2bf(-2.f*b.w);
        const int n   = kperm(code);
        const int off = n * 64 + ((((c16 * 16) ^ ((n & 7) << 4))) >> 1);
        *(bf16x8*)(emb_swz + off) = v;
    }
    if (id < K_) {
        const float4* row = (const float4*)(emb + (size_t)id * C_);
        float s0 = 0.f, s1 = 0.f, s2 = 0.f, s3 = 0.f;
        #pragma unroll
        for (int i = 0; i < C_ / 4; ++i) {
            float4 v = row[i];
            s0 = fmaf(v.x, v.x, s0);
            s1 = fmaf(v.y, v.y, s1);
            s2 = fmaf(v.z, v.z, s2);
            s3 = fmaf(v.w, v.w, s3);
        }
        e2[kperm(id)] = 1.0f + ((s0 + s1) + (s2 + s3));   // keeps dist' > 0
    }
}

// ---- kernel 2: fused MFMA argmin + gather + q_st + loss ------------------
// Block = 512 thr = 8 waves, owns 128 consecutive pixels (same b).
// Wave w: pixel half (w>>2)*64, K-quadrant q=w&3 (256 codes). A-reuse = 4:
// each emb ds_read_b128 feeds 4 MFMAs (4 pixel tiles in registers).
// emb chunks (128 permuted codes, 16 KB) double-buffered via global_load_lds.
//   D[row=code][col=pixel] = 1 + |e|^2 - 2 z.e  (positive)
// Select: sortable int = (bits(dist) & ~1023) | k_orig ; argmin = v_min_i32.
__global__ __launch_bounds__(512, 4) void vq_main(const float* __restrict__ z,
                                                  const float* __restrict__ emb,
                                                  const short* __restrict__ emb_swz,
                                                  const float* __restrict__ e2,
                                                  float* __restrict__ out,
                                                  float* __restrict__ psum) {
    __shared__ short zlds[PXB * 64];      // 16 KB, [px][ch], col ^= (px&7)<<4
    __shared__ short embuf[2][8192];      // 2 x 16 KB chunk double-buffer
    __shared__ float e2lds[K_];           // 4 KB (permuted)
    __shared__ int   smin[8][64];
    __shared__ int   cidx[PXB];
    __shared__ float red[8];

    const int tid  = threadIdx.x;
    const int lane = tid & 63;
    const int wave = __builtin_amdgcn_readfirstlane(tid >> 6);  // 0..7
    const int qd   = wave & 3;         // K-quadrant
    const int phx  = (wave >> 2) * 64; // pixel half base
    const int prow = lane & 15;        // code-in-tile row
    const int kgrp = lane >> 4;        // k-group 0..3

    const int blk = blockIdx.x;        // 0..511
    const int b   = blk >> 5;          // 32 blocks per image
    const int hw0 = (blk & 31) * PXB;
    const float* zp = z + (size_t)b * C_ * HW_ + hw0;   // + c*HW_ + p

    // ---- stage z -> swizzled LDS bf16 (each thread: 16 ch of one pixel) --
    {
        const int p  = tid & 127;
        const int c0 = tid >> 7;               // 0..3
        #pragma unroll
        for (int h = 0; h < 2; ++h) {
            const int cb = c0 * 16 + h * 8;    // channel base
            bf16x8 pack;
            #pragma unroll
            for (int i = 0; i < 8; ++i) pack[i] = f2bf(zp[(size_t)(cb + i) * HW_ + p]);
            const int wb = (p * 128 + ((cb * 2) ^ ((p & 7) << 4))) >> 1;
            *(bf16x8*)(zlds + wb) = pack;
        }
    }
    // ---- stage e2' (permuted, 1024 floats) ----
    e2lds[tid]       = e2[tid];
    e2lds[tid + 512] = e2[tid + 512];
    // ---- stage emb chunk 0 (16 KB: 8 waves x 2 KB) ----
    {
        short* dst = embuf[0] + wave * 1024;
        const short* s0 = emb_swz + wave * 1024 + lane * 8;
        gl_lds16(s0, dst);
        gl_lds16(s0 + 512, dst + 512);
    }
    __syncthreads();

    // ---- z fragments (B operand): 4 pixel tiles of this wave's half ----
    bf16x8 zf[4][2];
    #pragma unroll
    for (int pt = 0; pt < 4; ++pt) {
        const int pp = phx + pt * 16 + prow;
        #pragma unroll
        for (int ks = 0; ks < 2; ++ks) {
            const int rb = (pp * 128 + ((ks * 64 + kgrp * 16) ^ ((pp & 7) << 4))) >> 1;
            zf[pt][ks] = *(const bf16x8*)(zlds + rb);
        }
    }

    // lane-constant swizzle offsets (row&7 == prow&7 under the permutation)
    const int sa = ((kgrp * 16) ^ ((prow & 7) << 4)) >> 1;
    const int sb = ((64 + kgrp * 16) ^ ((prow & 7) << 4)) >> 1;

    int best[4] = {0x7FFFFFFF, 0x7FFFFFFF, 0x7FFFFFFF, 0x7FFFFFFF};
    int buf = 0;
    for (int chunk = 0; chunk < 8; ++chunk) {
        if (chunk < 7) {   // issue next-chunk stage BEFORE compute
            short* dst = embuf[buf ^ 1] + wave * 1024;
            const short* s0 = emb_swz + (chunk + 1) * 8192 + wave * 1024 + lane * 8;
            gl_lds16(s0, dst);
            gl_lds16(s0 + 512, dst + 512);
        }
        const short* eb = embuf[buf];
        #pragma unroll
        for (int ct = 0; ct < 2; ++ct) {
            const int lrow = qd * 32 + ct * 16;              // local row in chunk
            const bf16x8 a0 = *(const bf16x8*)(eb + (lrow + prow) * 64 + sa);
            const bf16x8 a1 = *(const bf16x8*)(eb + (lrow + prow) * 64 + sb);
            const int npos = chunk * 128 + lrow + kgrp * 4;  // permuted pos
            const int korg = qd * 256 + chunk * 32 + ct * 16 + kgrp * 4;
            const f32x4 ev = *(const f32x4*)(e2lds + npos);
            #pragma unroll
            for (int pt = 0; pt < 4; ++pt) {
                f32x4 acc = ev;
                acc = __builtin_amdgcn_mfma_f32_16x16x32_bf16(a0, zf[pt][0], acc, 0, 0, 0);
                acc = __builtin_amdgcn_mfma_f32_16x16x32_bf16(a1, zf[pt][1], acc, 0, 0, 0);
                #pragma unroll
                for (int r = 0; r < 4; ++r) {
                    const int s = (__builtin_bit_cast(int, acc[r]) & ~1023) | (korg + r);
                    best[pt] = min(best[pt], s);
                }
            }
        }
        __syncthreads();   // stage landed + compute done -> swap
        buf ^= 1;
    }

    // cross-lane combine over k-groups (bits 4,5 of lane)
    #pragma unroll
    for (int pt = 0; pt < 4; ++pt) {
        #pragma unroll
        for (int m = 16; m <= 32; m <<= 1)
            best[pt] = min(best[pt], __shfl_xor(best[pt], m));
        if (kgrp == 0) smin[wave][pt * 16 + prow] = best[pt];
    }
    __syncthreads();

    // cross-wave combine (4 quadrant-waves per pixel half)
    if (tid < PXB) {
        const int half = tid >> 6, lp = tid & 63;
        const int w0 = half * 4;
        int bb = min(min(smin[w0][lp], smin[w0 + 1][lp]),
                     min(smin[w0 + 2][lp], smin[w0 + 3][lp]));
        cidx[tid] = bb & 1023;
    }
    __syncthreads();

    // ---- output phase: q_st = z + (q - z), partial loss ----
    float* op = out + (size_t)b * C_ * HW_ + hw0;
    const int p  = tid & 127;
    const int c0 = tid >> 7;                  // 0..3
    const float* qrow = emb + (size_t)cidx[p] * C_;
    float sq = 0.f;
    #pragma unroll
    for (int i = 0; i < 16; ++i) {
        const int c = c0 * 16 + i;
        const float zv   = zp[(size_t)c * HW_ + p];
        const float q    = qrow[c];
        const float diff = q - zv;            // matches reference op order
        op[(size_t)c * HW_ + p] = zv + diff;  // q_st = z + (q - z)
        sq = fmaf(diff, diff, sq);
    }
    #pragma unroll
    for (int off = 32; off; off >>= 1) sq += __shfl_xor(sq, off);
    if (lane == 0) red[wave] = sq;
    __syncthreads();
    if (tid == 0) {
        float s = 0.f;
        #pragma unroll
        for (int w2 = 0; w2 < 8; ++w2) s += red[w2];
        psum[blk] = s;
    }
}

// ---- kernel 3: reduce partials -> loss -----------------------------------
__global__ __launch_bounds__(256) void vq_finalize(const float* __restrict__ psum,
                                                   float* __restrict__ out) {
    const int tid = threadIdx.x;
    float s = psum[tid] + psum[tid + 256];
    #pragma unroll
    for (int off = 32; off; off >>= 1) s += __shfl_xor(s, off);
    __shared__ float red[4];
    if ((tid & 63) == 0) red[tid >> 6] = s;
    __syncthreads();
    if (tid == 0)
        out[NELEM] = 1.25f * ((red[0] + red[1]) + (red[2] + red[3])) / (float)NELEM;
}

extern "C" void kernel_launch(void* const* d_in, const int* in_sizes, int n_in,
                              void* d_out, int out_size, void* d_ws, size_t ws_size,
                              hipStream_t stream) {
    const float* z   = (const float*)d_in[0];   // [16,64,64,64]
    const float* emb = (const float*)d_in[1];   // [1024,64]
    float* out = (float*)d_out;                 // [4194304 q_st] ++ [1 loss]

    float* psum    = (float*)d_ws;              // 512 floats
    float* e2      = psum + NBLK;               // 1024 floats (permuted e2')
    short* emb_swz = (short*)(e2 + K_);         // 65536 bf16, permuted+swizzled

    vq_prep    <<<(K_ * C_) / (256 * 8), 256, 0, stream>>>(emb, e2, emb_swz);
    vq_main    <<<NBLK, 512, 0, stream>>>(z, emb, emb_swz, e2, out, psum);
    vq_finalize<<<1,    256, 0, stream>>>(psum, out);
}